// Round 1
// baseline (487.495 us; speedup 1.0000x reference)
//
#include <hip/hip_runtime.h>
#include <hip/hip_bf16.h>
#include <stdint.h>

typedef __attribute__((ext_vector_type(8))) __bf16 bf16x8;
typedef __attribute__((ext_vector_type(4))) float f32x4;

static __device__ __forceinline__ ushort f2bf(float f) {
  union { float f; uint32_t u; } v; v.f = f;
  uint32_t u = v.u;
  u += 0x7fffu + ((u >> 16) & 1u);
  return (ushort)(u >> 16);
}

// ---------------- cast x (fp32) -> bf16, same layout ----------------
__global__ __launch_bounds__(256) void cast_f32_bf16(
    const float* __restrict__ in, ushort* __restrict__ out, int n) {
  int i = (blockIdx.x * 256 + threadIdx.x) * 4;
  if (i >= n) return;
  float4 v = *(const float4*)&in[i];
  ushort4 o;
  o.x = f2bf(v.x); o.y = f2bf(v.y); o.z = f2bf(v.z); o.w = f2bf(v.w);
  *(ushort4*)&out[i] = o;
}

// ------------- transpose-cast W (K x N fp32) -> Wt (N x K bf16) -------------
__global__ __launch_bounds__(256) void transpose_cast(
    const float* __restrict__ W, ushort* __restrict__ Wt, int K, int N) {
  __shared__ ushort tile[32][33];
  int n0 = blockIdx.x * 32, k0 = blockIdx.y * 32;
  int tx = threadIdx.x, ty = threadIdx.y;
  #pragma unroll
  for (int r = ty; r < 32; r += 8)
    tile[r][tx] = f2bf(W[(size_t)(k0 + r) * N + n0 + tx]);
  __syncthreads();
  #pragma unroll
  for (int r = ty; r < 32; r += 8)
    Wt[(size_t)(n0 + r) * K + k0 + tx] = tile[tx][r];
}

// ---------------- GEMM: C[M,N] = A[M,K] * Bt[N,K]^T (bf16 in, fp32 acc) ------
// MODE 1: scatter epilogue -> Q (B,H,T,D), K (B,H,T,D), V^T (B,H,D,T), bf16
// MODE 2: fp32 row-major C
template <int MODE>
__global__ __launch_bounds__(256) void gemm_bt(
    const ushort* __restrict__ A, const ushort* __restrict__ Bt,
    float* __restrict__ Cf, int M, int N, int K,
    ushort* __restrict__ Qo, ushort* __restrict__ Ko, ushort* __restrict__ Vo) {
  __shared__ ushort As[128][40];
  __shared__ ushort Bs[128][40];
  const int tid = threadIdx.x;
  const int lane = tid & 63;
  const int w = tid >> 6;
  const int wm = (w >> 1) * 64, wn = (w & 1) * 64;
  const int m0 = blockIdx.y * 128, n0 = blockIdx.x * 128;
  const int lr = lane & 15, kg = lane >> 4;
  const int srow = tid >> 2;
  const int sch = (tid & 3) << 3;

  f32x4 zero = {0.f, 0.f, 0.f, 0.f};
  f32x4 acc[4][4];
  #pragma unroll
  for (int i = 0; i < 4; i++)
    #pragma unroll
    for (int j = 0; j < 4; j++) acc[i][j] = zero;

  for (int k0 = 0; k0 < K; k0 += 32) {
    uint4 av0 = *(const uint4*)&A[(size_t)(m0 + srow) * K + k0 + sch];
    uint4 av1 = *(const uint4*)&A[(size_t)(m0 + 64 + srow) * K + k0 + sch];
    uint4 bv0 = *(const uint4*)&Bt[(size_t)(n0 + srow) * K + k0 + sch];
    uint4 bv1 = *(const uint4*)&Bt[(size_t)(n0 + 64 + srow) * K + k0 + sch];
    __syncthreads();
    *(uint4*)&As[srow][sch] = av0;
    *(uint4*)&As[64 + srow][sch] = av1;
    *(uint4*)&Bs[srow][sch] = bv0;
    *(uint4*)&Bs[64 + srow][sch] = bv1;
    __syncthreads();
    bf16x8 af[4], bfr[4];
    #pragma unroll
    for (int i = 0; i < 4; i++)
      af[i] = *(const bf16x8*)&As[wm + i * 16 + lr][kg * 8];
    #pragma unroll
    for (int j = 0; j < 4; j++)
      bfr[j] = *(const bf16x8*)&Bs[wn + j * 16 + lr][kg * 8];
    #pragma unroll
    for (int i = 0; i < 4; i++)
      #pragma unroll
      for (int j = 0; j < 4; j++)
        acc[i][j] = __builtin_amdgcn_mfma_f32_16x16x32_bf16(af[i], bfr[j],
                                                            acc[i][j], 0, 0, 0);
  }

  #pragma unroll
  for (int i = 0; i < 4; i++) {
    #pragma unroll
    for (int j = 0; j < 4; j++) {
      #pragma unroll
      for (int r = 0; r < 4; r++) {
        int mrow = m0 + wm + i * 16 + kg * 4 + r;
        int ncol = n0 + wn + j * 16 + lr;
        float vv = acc[i][j][r];
        if (MODE == 2) {
          Cf[(size_t)mrow * N + ncol] = vv;
        } else {
          int bb = mrow >> 11, tt = mrow & 2047;
          int which = ncol >> 10, c = ncol & 1023;
          int hh = c >> 6, dd = c & 63;
          ushort bv = f2bf(vv);
          size_t bh = (size_t)(bb * 16 + hh);
          if (which == 0)
            Qo[(bh * 2048 + tt) * 64 + dd] = bv;
          else if (which == 1)
            Ko[(bh * 2048 + tt) * 64 + dd] = bv;
          else
            Vo[(bh * 64 + dd) * 2048 + tt] = bv;
        }
      }
    }
  }
}

// ---------------- flash attention (causal), 1 wave / 16 q-rows ----------------
// Q,K: (B*H, T, D) bf16 ; Vt: (B*H, D, T) bf16 ; Y: (B, T, C) bf16
__global__ __launch_bounds__(64) void attn_fwd(
    const ushort* __restrict__ Q, const ushort* __restrict__ Kc,
    const ushort* __restrict__ Vt, ushort* __restrict__ Y) {
  constexpr float SC = 0.125f * 1.44269504088896340736f;  // scale * log2(e)
  __shared__ __bf16 Ps[16][88];
  const int lane = threadIdx.x;
  const int lr = lane & 15, kg = lane >> 4;
  const int blk = blockIdx.x;
  const int qt = blk & 127;  // T/16 = 128 tiles
  const int bh = blk >> 7;   // 0..63
  const int q0 = qt << 4;
  const ushort* Qp = Q + (size_t)bh * 2048 * 64;
  const ushort* Kp = Kc + (size_t)bh * 2048 * 64;
  const ushort* Vp = Vt + (size_t)bh * 64 * 2048;

  bf16x8 qf[2];
  qf[0] = *(const bf16x8*)&Qp[(size_t)(q0 + lr) * 64 + kg * 8];
  qf[1] = *(const bf16x8*)&Qp[(size_t)(q0 + lr) * 64 + 32 + kg * 8];

  f32x4 zero = {0.f, 0.f, 0.f, 0.f};
  f32x4 o[4];
  #pragma unroll
  for (int i = 0; i < 4; i++) o[i] = zero;
  float mrun[4], lrun[4];
  #pragma unroll
  for (int r = 0; r < 4; r++) { mrun[r] = -1e30f; lrun[r] = 0.f; }

  const int kend = q0 + 16;
  for (int k0 = 0; k0 < kend; k0 += 64) {
    // S = Q K^T for 64 keys (4 col-tiles)
    f32x4 s[4];
    #pragma unroll
    for (int ct = 0; ct < 4; ct++) {
      bf16x8 kf0 = *(const bf16x8*)&Kp[(size_t)(k0 + ct * 16 + lr) * 64 + kg * 8];
      bf16x8 kf1 =
          *(const bf16x8*)&Kp[(size_t)(k0 + ct * 16 + lr) * 64 + 32 + kg * 8];
      f32x4 z = zero;
      z = __builtin_amdgcn_mfma_f32_16x16x32_bf16(qf[0], kf0, z, 0, 0, 0);
      z = __builtin_amdgcn_mfma_f32_16x16x32_bf16(qf[1], kf1, z, 0, 0, 0);
      s[ct] = z;
    }
    // scale + causal mask (in log2 units), per-row local max
    float mx[4];
    #pragma unroll
    for (int r = 0; r < 4; r++) {
      int qi = q0 + kg * 4 + r;
      float a0 = -1e30f;
      #pragma unroll
      for (int ct = 0; ct < 4; ct++) {
        int kj = k0 + ct * 16 + lr;
        float z = s[ct][r] * SC;
        if (kj > qi) z = -1e30f;
        s[ct][r] = z;
        a0 = fmaxf(a0, z);
      }
      mx[r] = a0;
    }
    // butterfly max across the 16 lanes holding this row
    #pragma unroll
    for (int r = 0; r < 4; r++) {
      float v = mx[r];
      v = fmaxf(v, __shfl_xor(v, 1));
      v = fmaxf(v, __shfl_xor(v, 2));
      v = fmaxf(v, __shfl_xor(v, 4));
      v = fmaxf(v, __shfl_xor(v, 8));
      mx[r] = v;
    }
    float corr[4], rs[4];
    #pragma unroll
    for (int r = 0; r < 4; r++) {
      float mnew = fmaxf(mrun[r], mx[r]);
      corr[r] = exp2f(mrun[r] - mnew);
      mrun[r] = mnew;
      float sum = 0.f;
      #pragma unroll
      for (int ct = 0; ct < 4; ct++) {
        float p = exp2f(s[ct][r] - mnew);
        sum += p;
        Ps[kg * 4 + r][ct * 16 + lr] = (__bf16)p;
      }
      rs[r] = sum;
    }
    #pragma unroll
    for (int r = 0; r < 4; r++) {
      float v = rs[r];
      v += __shfl_xor(v, 1);
      v += __shfl_xor(v, 2);
      v += __shfl_xor(v, 4);
      v += __shfl_xor(v, 8);
      lrun[r] = lrun[r] * corr[r] + v;
    }
    #pragma unroll
    for (int dt = 0; dt < 4; dt++) {
      #pragma unroll
      for (int r = 0; r < 4; r++) o[dt][r] *= corr[r];
    }
    // P fragments from LDS (A-operand), V^T fragments from global (B-operand)
    bf16x8 pa[2];
    pa[0] = *(const bf16x8*)&Ps[lr][kg * 8];
    pa[1] = *(const bf16x8*)&Ps[lr][32 + kg * 8];
    #pragma unroll
    for (int dt = 0; dt < 4; dt++) {
      bf16x8 vf0 =
          *(const bf16x8*)&Vp[(size_t)(dt * 16 + lr) * 2048 + k0 + kg * 8];
      bf16x8 vf1 =
          *(const bf16x8*)&Vp[(size_t)(dt * 16 + lr) * 2048 + k0 + 32 + kg * 8];
      o[dt] = __builtin_amdgcn_mfma_f32_16x16x32_bf16(pa[0], vf0, o[dt], 0, 0, 0);
      o[dt] = __builtin_amdgcn_mfma_f32_16x16x32_bf16(pa[1], vf1, o[dt], 0, 0, 0);
    }
  }

  // epilogue: divide by l, write Y (B,T,C) bf16
  const int b = bh >> 4, h = bh & 15;
  float inv[4];
  #pragma unroll
  for (int r = 0; r < 4; r++) inv[r] = 1.f / lrun[r];
  #pragma unroll
  for (int dt = 0; dt < 4; dt++) {
    #pragma unroll
    for (int r = 0; r < 4; r++) {
      size_t t = (size_t)q0 + kg * 4 + r;
      Y[((size_t)b * 2048 + t) * 1024 + h * 64 + dt * 16 + lr] =
          f2bf(o[dt][r] * inv[r]);
    }
  }
}

extern "C" void kernel_launch(void* const* d_in, const int* in_sizes, int n_in,
                              void* d_out, int out_size, void* d_ws,
                              size_t ws_size, hipStream_t stream) {
  const float* x = (const float*)d_in[0];
  const float* Wa = (const float*)d_in[1];
  const float* Wp = (const float*)d_in[2];
  float* out = (float*)d_out;

  char* ws = (char*)d_ws;
  size_t off = 0;
  auto carve = [&](size_t bytes) {
    void* p = ws + off;
    off += (bytes + 255) & ~(size_t)255;
    return p;
  };
  ushort* Xb = (ushort*)carve(8192ull * 1024 * 2);
  ushort* Wat = (ushort*)carve(3072ull * 1024 * 2);
  ushort* Wpt = (ushort*)carve(1024ull * 1024 * 2);
  ushort* Qh = (ushort*)carve(64ull * 2048 * 64 * 2);
  ushort* Kh = (ushort*)carve(64ull * 2048 * 64 * 2);
  ushort* Vt = (ushort*)carve(64ull * 64 * 2048 * 2);
  ushort* Yb = (ushort*)carve(8192ull * 1024 * 2);

  cast_f32_bf16<<<8192, 256, 0, stream>>>(x, Xb, 8192 * 1024);
  transpose_cast<<<dim3(96, 32), dim3(32, 8), 0, stream>>>(Wa, Wat, 1024, 3072);
  transpose_cast<<<dim3(32, 32), dim3(32, 8), 0, stream>>>(Wp, Wpt, 1024, 1024);
  gemm_bt<1><<<dim3(24, 64), 256, 0, stream>>>(Xb, Wat, nullptr, 8192, 3072,
                                               1024, Qh, Kh, Vt);
  attn_fwd<<<8192, 64, 0, stream>>>(Qh, Kh, Vt, Yb);
  gemm_bt<2><<<dim3(8, 64), 256, 0, stream>>>(Yb, Wpt, out, 8192, 1024, 1024,
                                              nullptr, nullptr, nullptr);
}

// Round 2
// 361.707 us; speedup vs baseline: 1.3478x; 1.3478x over previous
//
#include <hip/hip_runtime.h>
#include <hip/hip_bf16.h>
#include <stdint.h>

typedef __attribute__((ext_vector_type(8))) __bf16 bf16x8;
typedef __attribute__((ext_vector_type(4))) float f32x4;

static __device__ __forceinline__ ushort f2bf(float f) {
  union { float f; uint32_t u; } v; v.f = f;
  uint32_t u = v.u;
  u += 0x7fffu + ((u >> 16) & 1u);
  return (ushort)(u >> 16);
}

// ---------------- cast x (fp32) -> bf16, same layout ----------------
__global__ __launch_bounds__(256) void cast_f32_bf16(
    const float* __restrict__ in, ushort* __restrict__ out, int n) {
  int i = (blockIdx.x * 256 + threadIdx.x) * 4;
  if (i >= n) return;
  float4 v = *(const float4*)&in[i];
  ushort4 o;
  o.x = f2bf(v.x); o.y = f2bf(v.y); o.z = f2bf(v.z); o.w = f2bf(v.w);
  *(ushort4*)&out[i] = o;
}

// ------------- transpose-cast W (K x N fp32) -> Wt (N x K bf16) -------------
__global__ __launch_bounds__(256) void transpose_cast(
    const float* __restrict__ W, ushort* __restrict__ Wt, int K, int N) {
  __shared__ ushort tile[32][33];
  int n0 = blockIdx.x * 32, k0 = blockIdx.y * 32;
  int tx = threadIdx.x, ty = threadIdx.y;
  #pragma unroll
  for (int r = ty; r < 32; r += 8)
    tile[r][tx] = f2bf(W[(size_t)(k0 + r) * N + n0 + tx]);
  __syncthreads();
  #pragma unroll
  for (int r = ty; r < 32; r += 8)
    Wt[(size_t)(n0 + r) * K + k0 + tx] = tile[tx][r];
}

// ---------------- GEMM: C[M,N] = A[M,K] * Bt[N,K]^T (bf16 in, fp32 acc) ------
// MODE 1: scatter epilogue -> Q (B,H,T,D), K (B,H,T,D), V^T (B,H,D,T), bf16
// MODE 2: fp32 row-major C
template <int MODE>
__global__ __launch_bounds__(256) void gemm_bt(
    const ushort* __restrict__ A, const ushort* __restrict__ Bt,
    float* __restrict__ Cf, int M, int N, int K,
    ushort* __restrict__ Qo, ushort* __restrict__ Ko, ushort* __restrict__ Vo) {
  __shared__ ushort As[128][40];
  __shared__ ushort Bs[128][40];
  const int tid = threadIdx.x;
  const int lane = tid & 63;
  const int w = tid >> 6;
  const int wm = (w >> 1) * 64, wn = (w & 1) * 64;
  const int m0 = blockIdx.y * 128, n0 = blockIdx.x * 128;
  const int lr = lane & 15, kg = lane >> 4;
  const int srow = tid >> 2;
  const int sch = (tid & 3) << 3;

  f32x4 zero = {0.f, 0.f, 0.f, 0.f};
  f32x4 acc[4][4];
  #pragma unroll
  for (int i = 0; i < 4; i++)
    #pragma unroll
    for (int j = 0; j < 4; j++) acc[i][j] = zero;

  for (int k0 = 0; k0 < K; k0 += 32) {
    uint4 av0 = *(const uint4*)&A[(size_t)(m0 + srow) * K + k0 + sch];
    uint4 av1 = *(const uint4*)&A[(size_t)(m0 + 64 + srow) * K + k0 + sch];
    uint4 bv0 = *(const uint4*)&Bt[(size_t)(n0 + srow) * K + k0 + sch];
    uint4 bv1 = *(const uint4*)&Bt[(size_t)(n0 + 64 + srow) * K + k0 + sch];
    __syncthreads();
    *(uint4*)&As[srow][sch] = av0;
    *(uint4*)&As[64 + srow][sch] = av1;
    *(uint4*)&Bs[srow][sch] = bv0;
    *(uint4*)&Bs[64 + srow][sch] = bv1;
    __syncthreads();
    bf16x8 af[4], bfr[4];
    #pragma unroll
    for (int i = 0; i < 4; i++)
      af[i] = *(const bf16x8*)&As[wm + i * 16 + lr][kg * 8];
    #pragma unroll
    for (int j = 0; j < 4; j++)
      bfr[j] = *(const bf16x8*)&Bs[wn + j * 16 + lr][kg * 8];
    #pragma unroll
    for (int i = 0; i < 4; i++)
      #pragma unroll
      for (int j = 0; j < 4; j++)
        acc[i][j] = __builtin_amdgcn_mfma_f32_16x16x32_bf16(af[i], bfr[j],
                                                            acc[i][j], 0, 0, 0);
  }

  #pragma unroll
  for (int i = 0; i < 4; i++) {
    #pragma unroll
    for (int j = 0; j < 4; j++) {
      #pragma unroll
      for (int r = 0; r < 4; r++) {
        int mrow = m0 + wm + i * 16 + kg * 4 + r;
        int ncol = n0 + wn + j * 16 + lr;
        float vv = acc[i][j][r];
        if (MODE == 2) {
          Cf[(size_t)mrow * N + ncol] = vv;
        } else {
          int bb = mrow >> 11, tt = mrow & 2047;
          int which = ncol >> 10, c = ncol & 1023;
          int hh = c >> 6, dd = c & 63;
          ushort bv = f2bf(vv);
          size_t bh = (size_t)(bb * 16 + hh);
          if (which == 0)
            Qo[(bh * 2048 + tt) * 64 + dd] = bv;
          else if (which == 1)
            Ko[(bh * 2048 + tt) * 64 + dd] = bv;
          else
            Vo[(bh * 64 + dd) * 2048 + tt] = bv;
        }
      }
    }
  }
}

// ---------------- flash attention (causal), 1 wave / 64 q-rows ----------------
// Swapped QK^T (S^T in regs, q = lane&15), XOR-swizzled P tile in LDS.
// Q,K: (B*H, T, D) bf16 ; Vt: (B*H, D, T) bf16 ; Y: (B, T, C) bf16
__global__ __launch_bounds__(64) void attn_fwd(
    const ushort* __restrict__ Q, const ushort* __restrict__ Kc,
    const ushort* __restrict__ Vt, ushort* __restrict__ Y) {
  constexpr float SC = 0.125f * 1.44269504088896340736f;  // scale * log2(e)
  __shared__ ushort Ps[4][16][64];  // per row-tile P, [16 q][64 k], swizzled
  const int lane = threadIdx.x;
  const int lr = lane & 15, kg = lane >> 4;
  int blk = blockIdx.x;
  blk = (blk & 7) * 256 + (blk >> 3);  // XCD swizzle (2048 % 8 == 0, bijective)
  const int qb = blk & 31;  // 32 q-blocks of 64 rows
  const int bh = blk >> 5;  // 0..63
  const int q0 = qb << 6;
  const ushort* Qp = Q + (size_t)bh * 2048 * 64;
  const ushort* Kp = Kc + (size_t)bh * 2048 * 64;
  const ushort* Vp = Vt + (size_t)bh * 64 * 2048;
  const int swz = (lr & 7) << 4;

  bf16x8 qf[4][2];
  #pragma unroll
  for (int rt = 0; rt < 4; rt++) {
    qf[rt][0] = *(const bf16x8*)&Qp[(size_t)(q0 + rt * 16 + lr) * 64 + kg * 8];
    qf[rt][1] =
        *(const bf16x8*)&Qp[(size_t)(q0 + rt * 16 + lr) * 64 + 32 + kg * 8];
  }

  f32x4 zero = {0.f, 0.f, 0.f, 0.f};
  f32x4 o[4][4];
  #pragma unroll
  for (int rt = 0; rt < 4; rt++)
    #pragma unroll
    for (int dt = 0; dt < 4; dt++) o[rt][dt] = zero;
  float mrun[4], lrun[4];
  #pragma unroll
  for (int rt = 0; rt < 4; rt++) { mrun[rt] = -1e30f; lrun[rt] = 0.f; }

  for (int k0 = 0; k0 <= q0; k0 += 64) {
    bf16x8 kf[4][2];
    #pragma unroll
    for (int ct = 0; ct < 4; ct++) {
      kf[ct][0] =
          *(const bf16x8*)&Kp[(size_t)(k0 + ct * 16 + lr) * 64 + kg * 8];
      kf[ct][1] =
          *(const bf16x8*)&Kp[(size_t)(k0 + ct * 16 + lr) * 64 + 32 + kg * 8];
    }
    const bool lastblk = (k0 == q0);  // wave-uniform
    f32x4 corrb[4];

    #pragma unroll
    for (int rt = 0; rt < 4; rt++) {
      // S^T tile: mfma(K-rows, Q-rows) -> C[k_local][q_local], q = lr per lane
      f32x4 s[4];
      #pragma unroll
      for (int ct = 0; ct < 4; ct++) {
        f32x4 z = zero;
        z = __builtin_amdgcn_mfma_f32_16x16x32_bf16(kf[ct][0], qf[rt][0], z, 0, 0, 0);
        z = __builtin_amdgcn_mfma_f32_16x16x32_bf16(kf[ct][1], qf[rt][1], z, 0, 0, 0);
        s[ct] = z;
      }
      float mx = -1e30f;
      if (lastblk) {
        const int qrow = q0 + rt * 16 + lr;
        #pragma unroll
        for (int ct = 0; ct < 4; ct++)
          #pragma unroll
          for (int r = 0; r < 4; r++) {
            int kj = k0 + ct * 16 + kg * 4 + r;
            float z = s[ct][r] * SC;
            z = (kj > qrow) ? -1e30f : z;
            s[ct][r] = z;
            mx = fmaxf(mx, z);
          }
      } else {
        #pragma unroll
        for (int ct = 0; ct < 4; ct++)
          #pragma unroll
          for (int r = 0; r < 4; r++) {
            float z = s[ct][r] * SC;
            s[ct][r] = z;
            mx = fmaxf(mx, z);
          }
      }
      // 2-shuffle reduce across the 4 lanes holding this q-row
      mx = fmaxf(mx, __shfl_xor(mx, 16));
      mx = fmaxf(mx, __shfl_xor(mx, 32));
      float mnew = fmaxf(mrun[rt], mx);
      float corr = exp2f(mrun[rt] - mnew);
      mrun[rt] = mnew;
      float sum = 0.f;
      #pragma unroll
      for (int ct = 0; ct < 4; ct++) {
        float p0 = exp2f(s[ct][0] - mnew);
        float p1 = exp2f(s[ct][1] - mnew);
        float p2 = exp2f(s[ct][2] - mnew);
        float p3 = exp2f(s[ct][3] - mnew);
        sum += (p0 + p1) + (p2 + p3);
        ushort4 pk;
        pk.x = f2bf(p0); pk.y = f2bf(p1); pk.z = f2bf(p2); pk.w = f2bf(p3);
        // k = ct*16 + kg*4 + r  -> byte base ct*32 + kg*8, XOR-swizzled
        *(ushort4*)((char*)&Ps[rt][lr][0] + ((ct * 32 + kg * 8) ^ swz)) = pk;
      }
      sum += __shfl_xor(sum, 16);
      sum += __shfl_xor(sum, 32);
      lrun[rt] = lrun[rt] * corr + sum;
      // broadcast corr to the lanes holding output rows q_local = kg*4+r
      f32x4 cb;
      #pragma unroll
      for (int r = 0; r < 4; r++) cb[r] = __shfl(corr, kg * 4 + r);
      corrb[rt] = cb;
    }

    // P fragments back from LDS (A-operand layout: row q=lr, k-contiguous)
    bf16x8 pa[4][2];
    #pragma unroll
    for (int rt = 0; rt < 4; rt++)
      #pragma unroll
      for (int h = 0; h < 2; h++)
        pa[rt][h] = *(const bf16x8*)((const char*)&Ps[rt][lr][0] +
                                     ((h * 64 + kg * 16) ^ swz));

    #pragma unroll
    for (int dt = 0; dt < 4; dt++) {
      bf16x8 vf0 =
          *(const bf16x8*)&Vp[(size_t)(dt * 16 + lr) * 2048 + k0 + kg * 8];
      bf16x8 vf1 =
          *(const bf16x8*)&Vp[(size_t)(dt * 16 + lr) * 2048 + k0 + 32 + kg * 8];
      #pragma unroll
      for (int rt = 0; rt < 4; rt++) {
        f32x4 t = o[rt][dt] * corrb[rt];
        t = __builtin_amdgcn_mfma_f32_16x16x32_bf16(pa[rt][0], vf0, t, 0, 0, 0);
        t = __builtin_amdgcn_mfma_f32_16x16x32_bf16(pa[rt][1], vf1, t, 0, 0, 0);
        o[rt][dt] = t;
      }
    }
  }

  // epilogue: divide by l, write Y (B,T,C) bf16
  const int b = bh >> 4, h = bh & 15;
  #pragma unroll
  for (int rt = 0; rt < 4; rt++) {
    float inv = 1.f / lrun[rt];
    f32x4 ib;
    #pragma unroll
    for (int r = 0; r < 4; r++) ib[r] = __shfl(inv, kg * 4 + r);
    #pragma unroll
    for (int dt = 0; dt < 4; dt++) {
      #pragma unroll
      for (int r = 0; r < 4; r++) {
        size_t t = (size_t)q0 + rt * 16 + kg * 4 + r;
        Y[((size_t)b * 2048 + t) * 1024 + h * 64 + dt * 16 + lr] =
            f2bf(o[rt][dt][r] * ib[r]);
      }
    }
  }
}

extern "C" void kernel_launch(void* const* d_in, const int* in_sizes, int n_in,
                              void* d_out, int out_size, void* d_ws,
                              size_t ws_size, hipStream_t stream) {
  const float* x = (const float*)d_in[0];
  const float* Wa = (const float*)d_in[1];
  const float* Wp = (const float*)d_in[2];
  float* out = (float*)d_out;

  char* ws = (char*)d_ws;
  size_t off = 0;
  auto carve = [&](size_t bytes) {
    void* p = ws + off;
    off += (bytes + 255) & ~(size_t)255;
    return p;
  };
  ushort* Xb = (ushort*)carve(8192ull * 1024 * 2);
  ushort* Wat = (ushort*)carve(3072ull * 1024 * 2);
  ushort* Wpt = (ushort*)carve(1024ull * 1024 * 2);
  ushort* Qh = (ushort*)carve(64ull * 2048 * 64 * 2);
  ushort* Kh = (ushort*)carve(64ull * 2048 * 64 * 2);
  ushort* Vt = (ushort*)carve(64ull * 64 * 2048 * 2);
  ushort* Yb = (ushort*)carve(8192ull * 1024 * 2);

  cast_f32_bf16<<<8192, 256, 0, stream>>>(x, Xb, 8192 * 1024);
  transpose_cast<<<dim3(96, 32), dim3(32, 8), 0, stream>>>(Wa, Wat, 1024, 3072);
  transpose_cast<<<dim3(32, 32), dim3(32, 8), 0, stream>>>(Wp, Wpt, 1024, 1024);
  gemm_bt<1><<<dim3(24, 64), 256, 0, stream>>>(Xb, Wat, nullptr, 8192, 3072,
                                               1024, Qh, Kh, Vt);
  attn_fwd<<<2048, 64, 0, stream>>>(Qh, Kh, Vt, Yb);
  gemm_bt<2><<<dim3(8, 64), 256, 0, stream>>>(Yb, Wpt, out, 8192, 1024, 1024,
                                              nullptr, nullptr, nullptr);
}